// Round 1
// baseline (711.772 us; speedup 1.0000x reference)
//
#include <hip/hip_runtime.h>
#include <stdint.h>

#define T_ 512
#define B_ 32
#define V_ 512
#define L_ 128
#define NEGF (-1000000000.0f)

// Signed-i8 quantization: E = exp(trans) in ~[0.55,1.83]; SE*1.83 < 127.
#define SE_Q 69.0f
#define SU_Q 127.0f
#define LOGC 9.078313f   /* log(SE_Q * SU_Q) */

// ---- DPP helpers (VALU pipe) ----------------------------------------------
template <int CTRL>
__device__ __forceinline__ int dppmov(int old_, int src) {
    return __builtin_amdgcn_update_dpp(old_, src, CTRL, 0xF, 0xF, false);
}
__device__ __forceinline__ float wave_max64(float x) {
    int xi = __float_as_int(x);
    x = fmaxf(x, __int_as_float(dppmov<0x111>(xi, xi))); xi = __float_as_int(x);
    x = fmaxf(x, __int_as_float(dppmov<0x112>(xi, xi))); xi = __float_as_int(x);
    x = fmaxf(x, __int_as_float(dppmov<0x114>(xi, xi))); xi = __float_as_int(x);
    x = fmaxf(x, __int_as_float(dppmov<0x118>(xi, xi))); xi = __float_as_int(x);
    x = fmaxf(x, __int_as_float(dppmov<0x142>(xi, xi))); xi = __float_as_int(x);
    x = fmaxf(x, __int_as_float(dppmov<0x143>(xi, xi)));
    return x;   // fully reduced in lane 63
}
__device__ __forceinline__ float wave_sum64(float x) {
    int xi = __float_as_int(x);
    x = x + __int_as_float(dppmov<0x111>(xi, xi)); xi = __float_as_int(x);
    x = x + __int_as_float(dppmov<0x112>(xi, xi)); xi = __float_as_int(x);
    x = x + __int_as_float(dppmov<0x114>(xi, xi)); xi = __float_as_int(x);
    x = x + __int_as_float(dppmov<0x118>(xi, xi)); xi = __float_as_int(x);
    x = x + __int_as_float(dppmov<0x142>(xi, xi)); xi = __float_as_int(x);
    x = x + __int_as_float(dppmov<0x143>(xi, xi));
    return x;
}
// monotonic float<->uint for LDS atomicMax (epilogue only)
__device__ __forceinline__ unsigned fkey(float f) {
    unsigned u = __float_as_uint(f);
    return (u & 0x80000000u) ? ~u : (u | 0x80000000u);
}
__device__ __forceinline__ float funkey(unsigned k) {
    unsigned u = (k & 0x80000000u) ? (k ^ 0x80000000u) : ~k;
    return __uint_as_float(u);
}
// full-rate i8 dot4 (v_dot4_i32_i8)
__device__ __forceinline__ int dot4(int a, int b, int c) {
#if defined(__has_builtin)
#if __has_builtin(__builtin_amdgcn_sdot4)
    return __builtin_amdgcn_sdot4(a, b, c, false);
#else
    int d;
    asm("v_dot4_i32_i8 %0, %1, %2, %3" : "=v"(d) : "v"(a), "v"(b), "v"(c));
    return d;
#endif
#else
    int d;
    asm("v_dot4_i32_i8 %0, %1, %2, %3" : "=v"(d) : "v"(a), "v"(b), "v"(c));
    return d;
#endif
}

// ---------------- prep: quantize E, row-major packed-i8 for dot4 ------------
// Layout: Et dword o = (j*512 + i)*4 + d  holds packed E[i][16j+4d .. 16j+4d+3].
// asg_main lane (row) i loads er4[j] = ((uint4*)Et)[j*512 + i]  (coalesced).
__global__ void asg_prep(const float* __restrict__ trans, uint32_t* __restrict__ Et) {
    int o = blockIdx.x * blockDim.x + threadIdx.x;      // 0 .. 65535
    int d = o & 3;
    int i = (o >> 2) & 511;
    int j = o >> 11;                                    // 0..31
    int k0 = 16 * j + 4 * d;
    const float4 tv = *(const float4*)(trans + (size_t)i * V_ + k0);
    uint32_t q0 = (uint32_t)fminf(127.0f, __expf(tv.x) * SE_Q + 0.5f);
    uint32_t q1 = (uint32_t)fminf(127.0f, __expf(tv.y) * SE_Q + 0.5f);
    uint32_t q2 = (uint32_t)fminf(127.0f, __expf(tv.z) * SE_Q + 0.5f);
    uint32_t q3 = (uint32_t)fminf(127.0f, __expf(tv.w) * SE_Q + 0.5f);
    Et[(size_t)o] = q0 | (q1 << 8) | (q2 << 16) | (q3 << 24);
}

// ---------------- fused main: blocks 0..31 = FCC(b), 32..63 = FAC(b-32) -----
// FCC (dot4 rewrite): each of 512 threads owns one row of E, register-resident
// as 128 packed-i8 dwords. Per step: wave-local max (DPP + readlane), u8
// quantized vs the OWN wave max, quad-packed to LDS; ONE barrier; consumers
// read 8 wave maxes + u chunks (uniform broadcast ds_read_b128) and combine
// 8 per-chunk i32 dot4 partials in fp32 with scales exp(mw - m). No MFMA,
// no in-loop atomics, one barrier/step, double-buffered LDS.
__global__ __attribute__((amdgpu_flat_work_group_size(512, 512),
                          amdgpu_waves_per_eu(2, 2)))
void asg_main(
    const float* __restrict__ lp, const uint32_t* __restrict__ Et,
    const float* __restrict__ trans, const int* __restrict__ targets,
    const int* __restrict__ ilen, const int* __restrict__ tlen,
    float* __restrict__ fcc_ws, float* __restrict__ fac_ws)
{
    __shared__ float facb[256];                           // fac double buffer
    __shared__ __align__(16) uint32_t u_lds[2][128];      // u8[512] x2 buffers
    __shared__ __align__(16) float   mw_lds[2][8];        // per-wave maxes x2
    __shared__ unsigned mslotE;
    __shared__ float sumf;

    const int bb  = blockIdx.x;
    const int tid = threadIdx.x;

    if (bb < B_) {
        // ================= FCC ============================================
        const int b    = bb;
        const int lane = tid & 63;
        const int w    = tid >> 6;              // wave 0..7 = K-chunk owner
        const int Tlen = ilen[b];

        // E row (tid) as 32 x uint4 of packed i8 — coalesced one-time load
        uint4 er4[32];
        {
            const uint4* Eq = (const uint4*)Et;
            #pragma unroll
            for (int j = 0; j < 32; ++j) er4[j] = Eq[j * 512 + tid];
        }

        float alpha = lp[(size_t)b * V_ + tid];
        float lpv   = lp[(size_t)1 * (B_ * V_) + (size_t)b * V_ + tid];
        if (tid == 0) { mslotE = 0u; sumf = 0.0f; }
        __syncthreads();

        for (int t = 1; t < Tlen; ++t) {
            const int bf = t & 1;

            // prefetch next lp (in flight across the whole step)
            int tn = (t + 1 < Tlen) ? (t + 1) : t;
            float lpv_n = lp[(size_t)tn * (B_ * V_) + (size_t)b * V_ + tid];

            // ---- wave-local max, broadcast to all lanes via readlane(63)
            float mwp = wave_max64(alpha);
            float mw  = __int_as_float(
                __builtin_amdgcn_readlane(__float_as_int(mwp), 63));

            // ---- u8 quantized u = exp(alpha - mw) <= 1, quad-packed
            {
                float u = __expf(alpha - mw);
                uint32_t qu = (uint32_t)(u * SU_Q + 0.5f);
                int pv = (int)(qu << (8 * (tid & 3)));
                pv |= dppmov<0xB1>(pv, pv);
                pv |= dppmov<0x4E>(pv, pv);
                if ((tid & 3) == 0) u_lds[bf][tid >> 2] = (uint32_t)pv;
            }
            if (lane == 0) mw_lds[bf][w] = mw;
            __syncthreads();                               // ONE barrier/step

            // ---- global max + per-chunk scales (uniform work, all lanes)
            float4 m0 = *(const float4*)&mw_lds[bf][0];
            float4 m1 = *(const float4*)&mw_lds[bf][4];
            float m = fmaxf(fmaxf(fmaxf(m0.x, m0.y), fmaxf(m0.z, m0.w)),
                            fmaxf(fmaxf(m1.x, m1.y), fmaxf(m1.z, m1.w)));
            float sarr[8];
            sarr[0] = __expf(m0.x - m); sarr[1] = __expf(m0.y - m);
            sarr[2] = __expf(m0.z - m); sarr[3] = __expf(m0.w - m);
            sarr[4] = __expf(m1.x - m); sarr[5] = __expf(m1.y - m);
            sarr[6] = __expf(m1.z - m); sarr[7] = __expf(m1.w - m);

            // ---- 128 x v_dot4_i32_i8: row(tid) . u, 8 chunks of K=64
            float accf = 0.0f;
            #pragma unroll
            for (int c = 0; c < 8; ++c) {
                const uint4* up = (const uint4*)&u_lds[bf][16 * c];
                int p0 = 0, p1 = 0;                        // 2 chains for ILP
                #pragma unroll
                for (int jj = 0; jj < 4; ++jj) {
                    uint4 uv = up[jj];                     // uniform broadcast
                    uint4 ev = er4[4 * c + jj];
                    p0 = dot4((int)ev.x, (int)uv.x, p0);
                    p1 = dot4((int)ev.y, (int)uv.y, p1);
                    p0 = dot4((int)ev.z, (int)uv.z, p0);
                    p1 = dot4((int)ev.w, (int)uv.w, p1);
                }
                accf = fmaf(sarr[c], (float)(p0 + p1), accf);
            }

            alpha = lpv + (m - LOGC) + __logf(accf);
            lpv = lpv_n;
        }

        // ---- epilogue: exact f32 logsumexp over the 512 alphas
        {
            float mx = wave_max64(alpha);
            if (lane == 63) atomicMax(&mslotE, fkey(mx));
        }
        __syncthreads();
        float m2 = funkey(mslotE);
        {
            float sv = wave_sum64(__expf(alpha - m2));
            if (lane == 63) atomicAdd(&sumf, sv);
        }
        __syncthreads();
        if (tid == 0) fcc_ws[b] = m2 + __logf(sumf);
    } else {
        // ================= FAC (threads 0..127 active) =====================
        const int b = bb - B_;
        const int l = tid;
        const bool active = (l < L_);
        const int Tlen = ilen[b];
        const int Llen = tlen[b];

        const int tl  = active ? targets[b * L_ + l] : 0;
        const int tlm = (active && l > 0) ? targets[b * L_ + l - 1] : 0;
        const float ts = active ? trans[(size_t)tl * V_ + tl] : 0.0f;
        const float tp = (active && l > 0) ? trans[(size_t)tl * V_ + tlm] : 0.0f;

        float beta = (l == 0) ? lp[(size_t)b * V_ + tl] : NEGF;
        float em_next = active ? lp[(size_t)1 * (B_ * V_) + (size_t)b * V_ + tl] : 0.0f;

        for (int t = 1; t < Tlen; ++t) {
            float* buf = facb + (t & 1) * L_;
            if (active) buf[l] = beta;
            __syncthreads();
            float prev = (active && l > 0) ? buf[l - 1] : NEGF;
            float em = em_next;
            if (active && t + 1 < Tlen)
                em_next = lp[(size_t)(t + 1) * (B_ * V_) + (size_t)b * V_ + tl];
            if (active) {
                float st = beta + ts;
                float mv = prev + tp;
                float mx = fmaxf(st, mv);
                float mn = fminf(st, mv);
                beta = em + mx + log1pf(__expf(mn - mx));
            }
        }
        if (active && l == Llen - 1) fac_ws[b] = beta;
    }
}

// ---------------- combine ---------------------------------------------------
__global__ void asg_combine(const float* __restrict__ fcc_ws,
                            const float* __restrict__ fac_ws,
                            float* __restrict__ out) {
    int i = threadIdx.x;
    if (i < B_) out[i] = fcc_ws[i] - fac_ws[i];
}

extern "C" void kernel_launch(void* const* d_in, const int* in_sizes, int n_in,
                              void* d_out, int out_size, void* d_ws, size_t ws_size,
                              hipStream_t stream) {
    const float* lp      = (const float*)d_in[0];
    const float* trans   = (const float*)d_in[1];
    const int*   targets = (const int*)d_in[2];
    const int*   ilen    = (const int*)d_in[3];
    const int*   tlen    = (const int*)d_in[4];
    float* out = (float*)d_out;

    uint32_t* Et     = (uint32_t*)d_ws;                    // 65536 dwords = 256 KB
    float*    fcc_ws = (float*)((char*)d_ws + 65536 * 4);
    float*    fac_ws = fcc_ws + B_;

    hipLaunchKernelGGL(asg_prep, dim3(256), dim3(256), 0, stream, trans, Et);
    hipLaunchKernelGGL(asg_main, dim3(2 * B_), dim3(512), 0, stream,
                       lp, Et, trans, targets, ilen, tlen, fcc_ws, fac_ws);
    hipLaunchKernelGGL(asg_combine, dim3(1), dim3(64), 0, stream, fcc_ws, fac_ws, out);
}

// Round 2
// 550.369 us; speedup vs baseline: 1.2933x; 1.2933x over previous
//
#include <hip/hip_runtime.h>
#include <stdint.h>

#define T_ 512
#define B_ 32
#define V_ 512
#define L_ 128
#define NEGF (-1000000000.0f)

// Signed-i8 quantization: E = exp(trans) in ~[0.55,1.83]; SE*1.83 < 127.
#define SE_Q 69.0f
#define SU_Q 127.0f
#define LOGC 9.078313f   /* log(SE_Q * SU_Q) */

typedef int v4i __attribute__((ext_vector_type(4)));

// ---- DPP helpers (VALU pipe) ----------------------------------------------
template <int CTRL>
__device__ __forceinline__ int dppmov(int old_, int src) {
    return __builtin_amdgcn_update_dpp(old_, src, CTRL, 0xF, 0xF, false);
}
__device__ __forceinline__ float wave_max64(float x) {
    int xi = __float_as_int(x);
    x = fmaxf(x, __int_as_float(dppmov<0x111>(xi, xi))); xi = __float_as_int(x);
    x = fmaxf(x, __int_as_float(dppmov<0x112>(xi, xi))); xi = __float_as_int(x);
    x = fmaxf(x, __int_as_float(dppmov<0x114>(xi, xi))); xi = __float_as_int(x);
    x = fmaxf(x, __int_as_float(dppmov<0x118>(xi, xi))); xi = __float_as_int(x);
    x = fmaxf(x, __int_as_float(dppmov<0x142>(xi, xi))); xi = __float_as_int(x);
    x = fmaxf(x, __int_as_float(dppmov<0x143>(xi, xi)));
    return x;   // fully reduced in lane 63
}
__device__ __forceinline__ float wave_sum64(float x) {
    int xi = __float_as_int(x);
    x = x + __int_as_float(dppmov<0x111>(xi, xi)); xi = __float_as_int(x);
    x = x + __int_as_float(dppmov<0x112>(xi, xi)); xi = __float_as_int(x);
    x = x + __int_as_float(dppmov<0x114>(xi, xi)); xi = __float_as_int(x);
    x = x + __int_as_float(dppmov<0x118>(xi, xi)); xi = __float_as_int(x);
    x = x + __int_as_float(dppmov<0x142>(xi, xi)); xi = __float_as_int(x);
    x = x + __int_as_float(dppmov<0x143>(xi, xi));
    return x;
}
// monotonic float<->uint for LDS atomicMax (epilogue only)
__device__ __forceinline__ unsigned fkey(float f) {
    unsigned u = __float_as_uint(f);
    return (u & 0x80000000u) ? ~u : (u | 0x80000000u);
}
__device__ __forceinline__ float funkey(unsigned k) {
    unsigned u = (k & 0x80000000u) ? (k ^ 0x80000000u) : ~k;
    return __uint_as_float(u);
}
// select element r (0..3) of a v4i — 3 cndmask, no scratch
__device__ __forceinline__ int sel4(v4i a, int r) {
    int x0 = (r & 1) ? a.y : a.x;
    int x1 = (r & 1) ? a.w : a.z;
    return (r & 2) ? x1 : x0;
}

// ---------------- prep: quantize E into MFMA A-fragment layout --------------
// asg_main thread tid (512 thr): w=tid>>6, lane=tid&63, q=lane>>4, n=lane&15.
// Wave w owns rows 64w..64w+63 as 4 M-tiles (tt) x 8 K-tiles (kt).
// A-frag for (tt,kt): lane holds A[m=64w+16tt+n][k=64kt+16q+4d+b], d=0..3,b=0..3.
// er4[tt*8+kt] = Eq[(tt*8+kt)*512 + tid]  ->  flat dword o = (qreg*512+tid)*4+d.
__global__ void asg_prep(const float* __restrict__ trans, uint32_t* __restrict__ Et) {
    int o = blockIdx.x * blockDim.x + threadIdx.x;      // 0 .. 65535
    int d    = o & 3;
    int tid  = (o >> 2) & 511;
    int qreg = o >> 11;                                  // 0..31
    int tt = qreg >> 3, kt = qreg & 7;
    int w = tid >> 6, lane = tid & 63;
    int q = lane >> 4, n = lane & 15;
    int m  = 64 * w + 16 * tt + n;
    int k0 = 64 * kt + 16 * q + 4 * d;
    const float* tp = trans + (size_t)m * V_ + k0;
    uint32_t q0 = (uint32_t)fminf(127.0f, __expf(tp[0]) * SE_Q + 0.5f);
    uint32_t q1 = (uint32_t)fminf(127.0f, __expf(tp[1]) * SE_Q + 0.5f);
    uint32_t q2 = (uint32_t)fminf(127.0f, __expf(tp[2]) * SE_Q + 0.5f);
    uint32_t q3 = (uint32_t)fminf(127.0f, __expf(tp[3]) * SE_Q + 0.5f);
    Et[(size_t)o] = q0 | (q1 << 8) | (q2 << 16) | (q3 << 24);
}

// ---------------- fused main: blocks 0..31 = FCC(b), 32..63 = FAC(b-32) -----
// FCC: E register-resident as i8 MFMA A-frags; per step:
//   wave max (DPP chain, lane 63) -> plain store mw_lds[w] -> barrier 1
//   all lanes: 2x ds_read_b128 of the 8 wave maxes + fmax tree (no atomics,
//   no slot read-back, no reset) -> quantize u8, quad-pack, store -> barrier 2
//   8x ds_read_b128 B-frags (u replicated across 16 cols), 32x
//   v_mfma_i32_16x16x64_i8, ownership select, alpha update.
// Single-buffered u_lds/mw_lds: the two barriers order the epochs (reads of
// step t are data-dependencies of alpha(t), so they complete before any wave
// reaches barrier 1 of step t+1).
__global__ __attribute__((amdgpu_flat_work_group_size(512, 512),
                          amdgpu_waves_per_eu(2, 2)))
void asg_main(
    const float* __restrict__ lp, const uint32_t* __restrict__ Et,
    const float* __restrict__ trans, const int* __restrict__ targets,
    const int* __restrict__ ilen, const int* __restrict__ tlen,
    float* __restrict__ fcc_ws, float* __restrict__ fac_ws)
{
    __shared__ float facb[256];                       // fac double buffer
    __shared__ __align__(16) uint32_t u_lds[128];     // u8[512] by row index
    __shared__ __align__(16) float mw_lds[8];         // per-wave maxes
    __shared__ unsigned mslotE;
    __shared__ float sumf;

    const int bb  = blockIdx.x;
    const int tid = threadIdx.x;

    if (bb < B_) {
        // ================= FCC ============================================
        const int b    = bb;
        const int lane = tid & 63;
        const int w    = tid >> 6;              // wave 0..7, rows 64w..64w+63
        const int q    = lane >> 4;             // 0..3
        const int n    = lane & 15;             // 0..15
        const int tt_o = n >> 2;                // owned tile
        const int rg_o = n & 3;                 // owned reg (row-in-4)
        const int i    = 64 * w + 16 * tt_o + 4 * q + rg_o;   // owned row
        const int Tlen = ilen[b];

        // er: 32 uint4 A-frags, lane-coalesced one-time load (no-spill path;
        // MFMA reads A from AGPR natively on gfx950's unified file)
        uint4 er4[32];
        {
            const uint4* Eq = (const uint4*)Et;
            #pragma unroll
            for (int t8 = 0; t8 < 32; ++t8) er4[t8] = Eq[t8 * 512 + tid];
        }

        float alpha = lp[(size_t)b * V_ + i];
        float lpv   = lp[(size_t)1 * (B_ * V_) + (size_t)b * V_ + i];
        if (tid == 0) { mslotE = 0u; sumf = 0.0f; }
        __syncthreads();

        for (int t = 1; t < Tlen; ++t) {
            // ---- publish wave max (lane 63 holds the full reduce)
            {
                float mx = wave_max64(alpha);
                if (lane == 63) mw_lds[w] = mx;
            }
            __syncthreads();                           // [mw visible]

            // ---- global max: broadcast-read 8 wave maxes, fmax tree
            float4 m0 = *(const float4*)&mw_lds[0];
            float4 m1 = *(const float4*)&mw_lds[4];
            float m = fmaxf(fmaxf(fmaxf(m0.x, m0.y), fmaxf(m0.z, m0.w)),
                            fmaxf(fmaxf(m1.x, m1.y), fmaxf(m1.z, m1.w)));

            // ---- u8 quantized u = exp(alpha - m), quad-packed to LDS byte i
            {
                float u = __expf(alpha - m);           // <= 1
                uint32_t qu = (uint32_t)(u * SU_Q + 0.5f);
                int pv = (int)(qu << (8 * (i & 3)));   // i&3 == lane bits 0-1
                pv |= dppmov<0xB1>(pv, pv);
                pv |= dppmov<0x4E>(pv, pv);
                if ((i & 3) == 0) u_lds[i >> 2] = (uint32_t)pv;
            }
            __syncthreads();                           // [u visible]

            // ---- B-frags: kt-th uint4 at byte 64kt + 16q (u8[k], all cols)
            uint4 bf[8];
            #pragma unroll
            for (int kt = 0; kt < 8; ++kt)
                bf[kt] = *(const uint4*)((const char*)u_lds + 64 * kt + 16 * q);

            // prefetch next lp (in flight over the MFMA phase; drained at
            // barrier 1 of step t+1, ~1.5k cycles away)
            int tn = (t + 1 < Tlen) ? (t + 1) : t;
            float lpv_n = lp[(size_t)tn * (B_ * V_) + (size_t)b * V_ + i];

            // ---- 32 MFMA: acc[tt] = sum_kt A(tt,kt) x B(kt)
            v4i a0, a1, a2, a3;
            {
                v4i z = {0, 0, 0, 0};
                a0 = z; a1 = z; a2 = z; a3 = z;
            }
            #pragma unroll
            for (int kt = 0; kt < 8; ++kt) {
                v4i bv = __builtin_bit_cast(v4i, bf[kt]);
                a0 = __builtin_amdgcn_mfma_i32_16x16x64_i8(
                        __builtin_bit_cast(v4i, er4[0 * 8 + kt]), bv, a0, 0, 0, 0);
                a1 = __builtin_amdgcn_mfma_i32_16x16x64_i8(
                        __builtin_bit_cast(v4i, er4[1 * 8 + kt]), bv, a1, 0, 0, 0);
                a2 = __builtin_amdgcn_mfma_i32_16x16x64_i8(
                        __builtin_bit_cast(v4i, er4[2 * 8 + kt]), bv, a2, 0, 0, 0);
                a3 = __builtin_amdgcn_mfma_i32_16x16x64_i8(
                        __builtin_bit_cast(v4i, er4[3 * 8 + kt]), bv, a3, 0, 0, 0);
            }

            // ---- ownership select: acc[tt_o][rg_o] (C: row=4q+reg, col=n)
            int s0 = sel4(a0, rg_o), s1 = sel4(a1, rg_o);
            int s2 = sel4(a2, rg_o), s3 = sel4(a3, rg_o);
            int y0 = (tt_o & 1) ? s1 : s0;
            int y1 = (tt_o & 1) ? s3 : s2;
            int acc = (tt_o & 2) ? y1 : y0;

            alpha = lpv + (m - LOGC) + __logf((float)acc);
            lpv = lpv_n;
        }

        // ---- epilogue: exact f32 logsumexp over the 512 alphas
        {
            float mx = wave_max64(alpha);
            if (lane == 63) atomicMax(&mslotE, fkey(mx));
        }
        __syncthreads();
        float m2 = funkey(mslotE);
        {
            float sv = wave_sum64(__expf(alpha - m2));
            if (lane == 63) atomicAdd(&sumf, sv);
        }
        __syncthreads();
        if (tid == 0) fcc_ws[b] = m2 + __logf(sumf);
    } else {
        // ================= FAC (threads 0..127 active) =====================
        const int b = bb - B_;
        const int l = tid;
        const bool active = (l < L_);
        const int Tlen = ilen[b];
        const int Llen = tlen[b];

        const int tl  = active ? targets[b * L_ + l] : 0;
        const int tlm = (active && l > 0) ? targets[b * L_ + l - 1] : 0;
        const float ts = active ? trans[(size_t)tl * V_ + tl] : 0.0f;
        const float tp = (active && l > 0) ? trans[(size_t)tl * V_ + tlm] : 0.0f;

        float beta = (l == 0) ? lp[(size_t)b * V_ + tl] : NEGF;
        float em_next = active ? lp[(size_t)1 * (B_ * V_) + (size_t)b * V_ + tl] : 0.0f;

        for (int t = 1; t < Tlen; ++t) {
            float* buf = facb + (t & 1) * L_;
            if (active) buf[l] = beta;
            __syncthreads();
            float prev = (active && l > 0) ? buf[l - 1] : NEGF;
            float em = em_next;
            if (active && t + 1 < Tlen)
                em_next = lp[(size_t)(t + 1) * (B_ * V_) + (size_t)b * V_ + tl];
            if (active) {
                float st = beta + ts;
                float mv = prev + tp;
                float mx = fmaxf(st, mv);
                float mn = fminf(st, mv);
                beta = em + mx + log1pf(__expf(mn - mx));
            }
        }
        if (active && l == Llen - 1) fac_ws[b] = beta;
    }
}

// ---------------- combine ---------------------------------------------------
__global__ void asg_combine(const float* __restrict__ fcc_ws,
                            const float* __restrict__ fac_ws,
                            float* __restrict__ out) {
    int i = threadIdx.x;
    if (i < B_) out[i] = fcc_ws[i] - fac_ws[i];
}

extern "C" void kernel_launch(void* const* d_in, const int* in_sizes, int n_in,
                              void* d_out, int out_size, void* d_ws, size_t ws_size,
                              hipStream_t stream) {
    const float* lp      = (const float*)d_in[0];
    const float* trans   = (const float*)d_in[1];
    const int*   targets = (const int*)d_in[2];
    const int*   ilen    = (const int*)d_in[3];
    const int*   tlen    = (const int*)d_in[4];
    float* out = (float*)d_out;

    uint32_t* Et     = (uint32_t*)d_ws;                    // 65536 dwords = 256 KB
    float*    fcc_ws = (float*)((char*)d_ws + 65536 * 4);
    float*    fac_ws = fcc_ws + B_;

    hipLaunchKernelGGL(asg_prep, dim3(256), dim3(256), 0, stream, trans, Et);
    hipLaunchKernelGGL(asg_main, dim3(2 * B_), dim3(512), 0, stream,
                       lp, Et, trans, targets, ilen, tlen, fcc_ws, fac_ws);
    hipLaunchKernelGGL(asg_combine, dim3(1), dim3(64), 0, stream, fcc_ws, fac_ws, out);
}